// Round 2
// baseline (493.650 us; speedup 1.0000x reference)
//
#include <hip/hip_runtime.h>
#include <hip/hip_bf16.h>

typedef unsigned short u16;
typedef __attribute__((ext_vector_type(8))) short bf16x8;
typedef __attribute__((ext_vector_type(4))) float f32x4;

#define MFMA16(a, b, c) __builtin_amdgcn_mfma_f32_16x16x32_bf16(a, b, c, 0, 0, 0)

__device__ __forceinline__ u16 f2b(float f) {
  union { float f; unsigned u; } x; x.f = f;
  return (u16)((x.u + 0x7fffu + ((x.u >> 16) & 1u)) >> 16);
}

__device__ __forceinline__ void gload_lds16(const void* g, void* l) {
  __builtin_amdgcn_global_load_lds(
      (const __attribute__((address_space(1))) void*)g,
      (__attribute__((address_space(3))) void*)l, 16, 0, 0);
}

// ---------------- weight f32 -> bf16 ----------------
__global__ __launch_bounds__(256) void cvt_kernel(const float* __restrict__ s,
                                                  u16* __restrict__ d, int n) {
  int i = blockIdx.x * 256 + threadIdx.x;
  if (i < n) d[i] = f2b(s[i]);
}

// ---------------- LN1 + cyclic shift + window partition (chunked) ----------------
__global__ __launch_bounds__(256) void ln1_win_kernel(
    const float* __restrict__ x, const float* __restrict__ w,
    const float* __restrict__ b, u16* __restrict__ xw, int tok0) {
  int wave = threadIdx.x >> 6, lane = threadIdx.x & 63;
  int tl = blockIdx.x * 4 + wave;           // chunk-local token
  int tok = tok0 + tl;                      // global window-order token
  int win = tok / 49, n = tok - win * 49;
  int bb = win >> 6, wi = win & 63;
  int wh = wi >> 3, ww = wi & 7;
  int rr = n / 7, cc = n - rr * 7;
  int hs = wh * 7 + rr + 3; if (hs >= 56) hs -= 56;
  int wsrc = ww * 7 + cc + 3; if (wsrc >= 56) wsrc -= 56;
  const float* xp = x + ((size_t)bb * 3136 + hs * 56 + wsrc) * 192;
  float v0 = xp[lane], v1 = xp[lane + 64], v2 = xp[lane + 128];
  float s = v0 + v1 + v2;
#pragma unroll
  for (int o = 32; o; o >>= 1) s += __shfl_xor(s, o, 64);
  float mean = s * (1.0f / 192.0f);
  float d0 = v0 - mean, d1 = v1 - mean, d2 = v2 - mean;
  float q = d0 * d0 + d1 * d1 + d2 * d2;
#pragma unroll
  for (int o = 32; o; o >>= 1) q += __shfl_xor(q, o, 64);
  float rstd = rsqrtf(q * (1.0f / 192.0f) + 1e-5f);
  u16* op = xw + (size_t)tl * 192;
  op[lane]       = f2b(d0 * rstd * w[lane]       + b[lane]);
  op[lane + 64]  = f2b(d1 * rstd * w[lane + 64]  + b[lane + 64]);
  op[lane + 128] = f2b(d2 * rstd * w[lane + 128] + b[lane + 128]);
}

// ---------------- LN2 (natural token order, chunked) ----------------
__global__ __launch_bounds__(256) void ln2_kernel(
    const float* __restrict__ x, const float* __restrict__ w,
    const float* __restrict__ b, u16* __restrict__ h1, int tok0) {
  int wave = threadIdx.x >> 6, lane = threadIdx.x & 63;
  int tl = blockIdx.x * 4 + wave;
  const float* xp = x + (size_t)(tok0 + tl) * 192;
  float v0 = xp[lane], v1 = xp[lane + 64], v2 = xp[lane + 128];
  float s = v0 + v1 + v2;
#pragma unroll
  for (int o = 32; o; o >>= 1) s += __shfl_xor(s, o, 64);
  float mean = s * (1.0f / 192.0f);
  float d0 = v0 - mean, d1 = v1 - mean, d2 = v2 - mean;
  float q = d0 * d0 + d1 * d1 + d2 * d2;
#pragma unroll
  for (int o = 32; o; o >>= 1) q += __shfl_xor(q, o, 64);
  float rstd = rsqrtf(q * (1.0f / 192.0f) + 1e-5f);
  u16* op = h1 + (size_t)tl * 192;
  op[lane]       = f2b(d0 * rstd * w[lane]       + b[lane]);
  op[lane + 64]  = f2b(d1 * rstd * w[lane + 64]  + b[lane + 64]);
  op[lane + 128] = f2b(d2 * rstd * w[lane + 128] + b[lane + 128]);
}

// ---------------- shared GEMM core: 64x64 tile, BK=32, 4 waves ----------------
template <int KDIM>
__device__ __forceinline__ void gemm_core(
    const u16* __restrict__ A, const u16* __restrict__ Bw,
    u16* As, u16* Bs, int m0, int n0, int wave, int lane, f32x4* acc) {
  const int c = wave * 64 + lane;
  const int srow = c >> 2;
  const int skc = (c & 3) ^ (srow & 3);
  const u16* ga = A + (size_t)(m0 + srow) * KDIM + skc * 8;
  const u16* gb = Bw + (size_t)(n0 + srow) * KDIM + skc * 8;
  u16* la = As + wave * 512;
  u16* lb = Bs + wave * 512;
  const int row = lane & 15, g = lane >> 4;
  const int ar = wave * 16 + row;
  for (int k0 = 0; k0 < KDIM; k0 += 32) {
    __syncthreads();
    gload_lds16(ga + k0, la);
    gload_lds16(gb + k0, lb);
    asm volatile("s_waitcnt vmcnt(0)" ::: "memory");
    __syncthreads();
    bf16x8 af = *(const bf16x8*)(As + ar * 32 + ((g ^ (ar & 3)) * 8));
#pragma unroll
    for (int nt = 0; nt < 4; ++nt) {
      int br = nt * 16 + row;
      bf16x8 bfr = *(const bf16x8*)(Bs + br * 32 + ((g ^ (br & 3)) * 8));
      acc[nt] = MFMA16(af, bfr, acc[nt]);
    }
  }
}

// ---------------- QKV GEMM (chunk-local A and q/k/v) ----------------
__global__ __launch_bounds__(256) void qkv_gemm(
    const u16* __restrict__ A, const u16* __restrict__ Bw,
    const float* __restrict__ qkvb,
    u16* __restrict__ qb, u16* __restrict__ kb, u16* __restrict__ vb,
    int tok0) {
  __shared__ __align__(16) u16 As[64 * 32], Bs[64 * 32];
  int wave = threadIdx.x >> 6, lane = threadIdx.x & 63;
  int m0 = blockIdx.x * 64, n0 = blockIdx.y * 64;
  f32x4 acc[4] = {{0,0,0,0},{0,0,0,0},{0,0,0,0},{0,0,0,0}};
  gemm_core<192>(A, Bw, As, Bs, m0, n0, wave, lane, acc);
  int col = lane & 15, g = lane >> 4;
  int win0 = tok0 / 49;
#pragma unroll
  for (int nt = 0; nt < 4; ++nt) {
    int j = n0 + nt * 16 + col;
    int which = j / 192, jj = j - which * 192;
    int hh = jj >> 5, d = jj & 31;
    u16* dst = which == 0 ? qb : (which == 1 ? kb : vb);
    float bv = qkvb[j];
#pragma unroll
    for (int reg = 0; reg < 4; ++reg) {
      int rg = tok0 + m0 + wave * 16 + 4 * g + reg;
      int win = rg / 49, n = rg - win * 49;
      dst[((size_t)((win - win0) * 6 + hh) * 49 + n) * 32 + d] =
          f2b(acc[nt][reg] + bv);
    }
  }
}

// ---------------- attention: one (window, head) per block ----------------
__global__ __launch_bounds__(256) void attn_kernel(
    const u16* __restrict__ qb, const u16* __restrict__ kb,
    const u16* __restrict__ vb, const float* __restrict__ rpb,
    const float* __restrict__ amask, u16* __restrict__ aout, int win0) {
  __shared__ __align__(16) u16 qs[64 * 32], ks[64 * 32], vst[32 * 64];
  __shared__ __align__(16) float S[64 * 68];
  __shared__ __align__(16) u16 P[64 * 64];
  int tid = threadIdx.x;
  int blk = blockIdx.x;
  int winl = blk / 6, head = blk - winl * 6;
  int wi = (win0 + winl) & 63;
  const size_t base = (size_t)(winl * 6 + head) * 49 * 32;
  {
    int row = tid >> 2, kcl = tid & 3;
    int phys = kcl ^ (row & 3);
    uint4 qv = make_uint4(0, 0, 0, 0), kv = qv, vv = qv;
    if (row < 49) {
      size_t o = base + (size_t)row * 32 + kcl * 8;
      qv = *(const uint4*)(qb + o);
      kv = *(const uint4*)(kb + o);
      vv = *(const uint4*)(vb + o);
    }
    *(uint4*)(qs + row * 32 + phys * 8) = qv;
    *(uint4*)(ks + row * 32 + phys * 8) = kv;
    alignas(16) u16 vu[8];
    *(uint4*)vu = vv;
    int c8 = kcl * 8;
    int kc = row >> 3;
#pragma unroll
    for (int j = 0; j < 8; ++j) {
      int d = c8 + j;
      vst[d * 64 + ((kc ^ (d & 7)) * 8) + (row & 7)] = vu[j];
    }
  }
  __syncthreads();
  int wave = tid >> 6, lane = tid & 63;
  int col = lane & 15, g = lane >> 4;
  {
    int ar = wave * 16 + col;
    bf16x8 af = *(const bf16x8*)(qs + ar * 32 + ((g ^ (ar & 3)) * 8));
    f32x4 zero = {0.f, 0.f, 0.f, 0.f};
#pragma unroll
    for (int nt = 0; nt < 4; ++nt) {
      int br = nt * 16 + col;
      bf16x8 bfr = *(const bf16x8*)(ks + br * 32 + ((g ^ (br & 3)) * 8));
      f32x4 sacc = MFMA16(af, bfr, zero);
#pragma unroll
      for (int reg = 0; reg < 4; ++reg)
        S[(wave * 16 + 4 * g + reg) * 68 + nt * 16 + col] = sacc[reg];
    }
  }
  __syncthreads();
  {
    int r = tid >> 2, p = tid & 3;
    int rb = (r < 49) ? r : 0;
    int i1 = rb / 7, j1 = rb - i1 * 7;
    const float scale = 0.17677669529663687f;
    const float* Srow = S + r * 68;
    float vals[16];
    float mx = -1e30f;
#pragma unroll
    for (int t = 0; t < 16; ++t) {
      int c = p * 16 + t;
      float v = -1e30f;
      if (c < 49) {
        int i2 = c / 7, j2 = c - i2 * 7;
        int ridx = (i1 - i2 + 6) * 13 + (j1 - j2 + 6);
        v = Srow[c] * scale + rpb[ridx * 6 + head] +
            amask[(size_t)wi * 2401 + rb * 49 + c];
      }
      vals[t] = v;
      mx = fmaxf(mx, v);
    }
    mx = fmaxf(mx, __shfl_xor(mx, 1, 64));
    mx = fmaxf(mx, __shfl_xor(mx, 2, 64));
    float se = 0.f;
#pragma unroll
    for (int t = 0; t < 16; ++t) {
      float e = __expf(vals[t] - mx);
      vals[t] = e;
      se += e;
    }
    se += __shfl_xor(se, 1, 64);
    se += __shfl_xor(se, 2, 64);
    float inv = 1.0f / se;
#pragma unroll
    for (int t = 0; t < 16; ++t) {
      int c = p * 16 + t;
      P[r * 64 + (((c >> 3) ^ (r & 7)) * 8) + (c & 7)] = f2b(vals[t] * inv);
    }
  }
  __syncthreads();
  {
    f32x4 oacc[2] = {{0,0,0,0},{0,0,0,0}};
    int ar = wave * 16 + col;
#pragma unroll
    for (int kt = 0; kt < 2; ++kt) {
      bf16x8 pf = *(const bf16x8*)(P + ar * 64 + (((kt * 4 + g) ^ (ar & 7)) * 8));
#pragma unroll
      for (int nt = 0; nt < 2; ++nt) {
        int d = nt * 16 + col;
        bf16x8 vf = *(const bf16x8*)(vst + d * 64 + (((kt * 4 + g) ^ (d & 7)) * 8));
        oacc[nt] = MFMA16(pf, vf, oacc[nt]);
      }
    }
#pragma unroll
    for (int nt = 0; nt < 2; ++nt)
#pragma unroll
      for (int reg = 0; reg < 4; ++reg) {
        int rloc = wave * 16 + 4 * g + reg;
        if (rloc < 49)
          aout[((size_t)winl * 49 + rloc) * 192 + head * 32 + nt * 16 + col] =
              f2b(oacc[nt][reg]);
      }
  }
}

// ---------------- proj GEMM + window reverse + unshift + residual ----------------
__global__ __launch_bounds__(256) void proj_gemm(
    const u16* __restrict__ A, const u16* __restrict__ Bw,
    const float* __restrict__ pb, const float* __restrict__ x,
    float* __restrict__ out, int tok0) {
  __shared__ __align__(16) u16 As[64 * 32], Bs[64 * 32];
  int wave = threadIdx.x >> 6, lane = threadIdx.x & 63;
  int m0 = blockIdx.x * 64, n0 = blockIdx.y * 64;
  f32x4 acc[4] = {{0,0,0,0},{0,0,0,0},{0,0,0,0},{0,0,0,0}};
  gemm_core<192>(A, Bw, As, Bs, m0, n0, wave, lane, acc);
  int col = lane & 15, g = lane >> 4;
#pragma unroll
  for (int nt = 0; nt < 4; ++nt) {
    int j = n0 + nt * 16 + col;
    float bv = pb[j];
#pragma unroll
    for (int reg = 0; reg < 4; ++reg) {
      int rg = tok0 + m0 + wave * 16 + 4 * g + reg;
      int win = rg / 49, n = rg - win * 49;
      int b_ = win >> 6, wi = win & 63;
      int wh = wi >> 3, ww = wi & 7;
      int rr = n / 7, cc = n - rr * 7;
      int hd_ = wh * 7 + rr + 3; if (hd_ >= 56) hd_ -= 56;
      int wd = ww * 7 + cc + 3; if (wd >= 56) wd -= 56;
      size_t t = (size_t)b_ * 3136 + hd_ * 56 + wd;
      out[t * 192 + j] = x[t * 192 + j] + acc[nt][reg] + bv;
    }
  }
}

// ---------------- fc1 GEMM + exact GELU (chunk-local) ----------------
__global__ __launch_bounds__(256) void fc1_gemm(
    const u16* __restrict__ A, const u16* __restrict__ Bw,
    const float* __restrict__ fb, u16* __restrict__ hmid) {
  __shared__ __align__(16) u16 As[64 * 32], Bs[64 * 32];
  int wave = threadIdx.x >> 6, lane = threadIdx.x & 63;
  int m0 = blockIdx.x * 64, n0 = blockIdx.y * 64;
  f32x4 acc[4] = {{0,0,0,0},{0,0,0,0},{0,0,0,0},{0,0,0,0}};
  gemm_core<192>(A, Bw, As, Bs, m0, n0, wave, lane, acc);
  int col = lane & 15, g = lane >> 4;
#pragma unroll
  for (int nt = 0; nt < 4; ++nt) {
    int j = n0 + nt * 16 + col;
    float bv = fb[j];
#pragma unroll
    for (int reg = 0; reg < 4; ++reg) {
      int r = m0 + wave * 16 + 4 * g + reg;
      float v = acc[nt][reg] + bv;
      float gl = 0.5f * v * (1.0f + erff(v * 0.70710678118654752f));
      hmid[(size_t)r * 768 + j] = f2b(gl);
    }
  }
}

// ---------------- fc2 GEMM + residual (chunk-local A, global out) ----------------
__global__ __launch_bounds__(256) void fc2_gemm(
    const u16* __restrict__ A, const u16* __restrict__ Bw,
    const float* __restrict__ fb, float* __restrict__ out, int tok0) {
  __shared__ __align__(16) u16 As[64 * 32], Bs[64 * 32];
  int wave = threadIdx.x >> 6, lane = threadIdx.x & 63;
  int m0 = blockIdx.x * 64, n0 = blockIdx.y * 64;
  f32x4 acc[4] = {{0,0,0,0},{0,0,0,0},{0,0,0,0},{0,0,0,0}};
  gemm_core<768>(A, Bw, As, Bs, m0, n0, wave, lane, acc);
  int col = lane & 15, g = lane >> 4;
#pragma unroll
  for (int nt = 0; nt < 4; ++nt) {
    int j = n0 + nt * 16 + col;
    float bv = fb[j];
#pragma unroll
    for (int reg = 0; reg < 4; ++reg) {
      int r = m0 + wave * 16 + 4 * g + reg;
      size_t o = (size_t)(tok0 + r) * 192 + j;
      out[o] = out[o] + acc[nt][reg] + bv;
    }
  }
}

extern "C" void kernel_launch(void* const* d_in, const int* in_sizes, int n_in,
                              void* d_out, int out_size, void* d_ws, size_t ws_size,
                              hipStream_t stream) {
  (void)in_sizes; (void)n_in; (void)out_size;
  const float* x     = (const float*)d_in[0];
  const float* amask = (const float*)d_in[1];
  const float* n1w   = (const float*)d_in[2];
  const float* n1b   = (const float*)d_in[3];
  const float* qkvw  = (const float*)d_in[4];
  const float* qkvb  = (const float*)d_in[5];
  const float* rpb   = (const float*)d_in[6];
  const float* projw = (const float*)d_in[7];
  const float* projb = (const float*)d_in[8];
  const float* n2w   = (const float*)d_in[9];
  const float* n2b   = (const float*)d_in[10];
  const float* fc1w  = (const float*)d_in[11];
  const float* fc1b  = (const float*)d_in[12];
  const float* fc2w  = (const float*)d_in[13];
  const float* fc2b  = (const float*)d_in[14];
  float* out = (float*)d_out;
  char* ws = (char*)d_ws;

  // weights live in the first 1 MB of ws
  u16* qkvw_bf = (u16*)(ws);
  u16* projw_bf = (u16*)(ws + 221184);
  u16* fc1w_bf = (u16*)(ws + 221184 + 73728);
  u16* fc2w_bf = (u16*)(ws + 221184 + 73728 + 294912);
  char* arena = ws + (1 << 20);
  size_t arena_sz = ws_size > (1 << 20) ? ws_size - (1 << 20) : 0;

  cvt_kernel<<<(110592 + 255) / 256, 256, 0, stream>>>(qkvw, qkvw_bf, 110592);
  cvt_kernel<<<(36864 + 255) / 256, 256, 0, stream>>>(projw, projw_bf, 36864);
  cvt_kernel<<<(147456 + 255) / 256, 256, 0, stream>>>(fc1w, fc1w_bf, 147456);
  cvt_kernel<<<(147456 + 255) / 256, 256, 0, stream>>>(fc2w, fc2w_bf, 147456);

  // ---- attention path, chunked over window groups ----
  // per-chunk bytes: 4 * Wc*49*192*2  (xw + q + k + v)
  int NCA = 1;
  while (NCA < 16 &&
         4ull * (size_t)(2048 / NCA) * 49 * 192 * 2 > arena_sz)
    NCA <<= 1;
  int Wc = 2048 / NCA;
  size_t Sx = (size_t)Wc * 49 * 192;   // elements (u16)
  for (int c = 0; c < NCA; ++c) {
    int win0 = c * Wc;
    int tok0 = win0 * 49;
    u16* xw_c = (u16*)arena;           // also reused as aout_c
    u16* qb = (u16*)arena + Sx;
    u16* kb = qb + Sx;
    u16* vb = kb + Sx;
    int rows = Wc * 49;
    ln1_win_kernel<<<rows / 4, 256, 0, stream>>>(x, n1w, n1b, xw_c, tok0);
    qkv_gemm<<<dim3(rows / 64, 9), 256, 0, stream>>>(xw_c, qkvw_bf, qkvb,
                                                     qb, kb, vb, tok0);
    attn_kernel<<<Wc * 6, 256, 0, stream>>>(qb, kb, vb, rpb, amask, xw_c, win0);
    proj_gemm<<<dim3(rows / 64, 3), 256, 0, stream>>>(xw_c, projw_bf, projb,
                                                      x, out, tok0);
  }

  // ---- MLP path, chunked over row groups ----
  // per-chunk bytes: rows_c * (192 + 768) * 2
  int NCM = 1;
  while (NCM < 32 && (size_t)(100352 / NCM) * 1920 > arena_sz) NCM <<= 1;
  int rows_c = 100352 / NCM;
  for (int c = 0; c < NCM; ++c) {
    int tok0 = c * rows_c;
    u16* h1_c = (u16*)arena;
    u16* hmid_c = h1_c + (size_t)rows_c * 192;
    ln2_kernel<<<rows_c / 4, 256, 0, stream>>>(out, n2w, n2b, h1_c, tok0);
    fc1_gemm<<<dim3(rows_c / 64, 12), 256, 0, stream>>>(h1_c, fc1w_bf, fc1b,
                                                        hmid_c);
    fc2_gemm<<<dim3(rows_c / 64, 3), 256, 0, stream>>>(hmid_c, fc2w_bf, fc2b,
                                                       out, tok0);
  }
}

// Round 4
// 390.305 us; speedup vs baseline: 1.2648x; 1.2648x over previous
//
#include <hip/hip_runtime.h>
#include <hip/hip_bf16.h>

typedef unsigned short u16;
typedef __attribute__((ext_vector_type(8))) short bf16x8;
typedef __attribute__((ext_vector_type(4))) float f32x4;

#define MFMA16(a, b, c) __builtin_amdgcn_mfma_f32_16x16x32_bf16(a, b, c, 0, 0, 0)

__device__ __forceinline__ u16 f2b(float f) {
  union { float f; unsigned u; } x; x.f = f;
  return (u16)((x.u + 0x7fffu + ((x.u >> 16) & 1u)) >> 16);
}

__device__ __forceinline__ void gload_lds16(const void* g, void* l) {
  __builtin_amdgcn_global_load_lds(
      (const __attribute__((address_space(1))) void*)g,
      (__attribute__((address_space(3))) void*)l, 16, 0, 0);
}

// stage 64 rows x 192 cols bf16, chunk(8xbf16) XOR-swizzled by row&7.
// LDS dest linear (wave-uniform base + lane*16), global source pre-swizzled.
__device__ __forceinline__ void stage_64x192(const u16* __restrict__ src,
                                             int stride, u16* dst, int wave,
                                             int lane) {
#pragma unroll
  for (int it = 0; it < 6; ++it) {
    int id = (it * 4 + wave) * 64 + lane;
    int row = id / 24, ph = id - row * 24;
    int lch = (ph & 24) | ((ph ^ (row & 7)) & 7);
    gload_lds16(src + (size_t)row * stride + lch * 8,
                dst + (it * 4 + wave) * 512);
  }
}

// stage 192 rows x 64 cols bf16 (8 chunks/row), same swizzle discipline.
__device__ __forceinline__ void stage_192x64(const u16* __restrict__ src,
                                             int stride, u16* dst, int wave,
                                             int lane) {
#pragma unroll
  for (int it = 0; it < 6; ++it) {
    int id = (it * 4 + wave) * 64 + lane;
    int row = id >> 3, ph = id & 7;
    int lch = ph ^ (row & 7);
    gload_lds16(src + (size_t)row * stride + lch * 8,
                dst + (it * 4 + wave) * 512);
  }
}

// ---------------- weight f32 -> bf16 ----------------
__global__ __launch_bounds__(256) void cvt_kernel(const float* __restrict__ s,
                                                  u16* __restrict__ d, int n) {
  int i = blockIdx.x * 256 + threadIdx.x;
  if (i < n) d[i] = f2b(s[i]);
}

// ---------------- fused LN1 + shift/window + QKV GEMM ----------------
__global__ __launch_bounds__(256, 2) void qkv_fused(
    const float* __restrict__ x, const float* __restrict__ n1w,
    const float* __restrict__ n1b, const u16* __restrict__ qkvw,
    const float* __restrict__ qkvb_, u16* __restrict__ qb,
    u16* __restrict__ kb, u16* __restrict__ vb, int tok0) {
  __shared__ __align__(16) u16 lds[36864];
  u16* sA = lds;
  u16* sB0 = lds + 12288;
  u16* sB1 = lds + 24576;
  int tid = threadIdx.x, wave = tid >> 6, lane = tid & 63;
  int g = lane >> 4, c = lane & 15, wr = wave * 16;
  int m0 = blockIdx.x * 64;
  // prefetch B chunk 0 while doing LN
  stage_64x192(qkvw, 192, sB0, wave, lane);
  // LN1 over shifted-window source rows (C-layout in regs)
  float vals[12][4];
  int srcrow[4];
#pragma unroll
  for (int reg = 0; reg < 4; ++reg) {
    int rg = tok0 + m0 + wr + 4 * g + reg;
    int win = rg / 49, n = rg - win * 49;
    int bb = win >> 6, wi = win & 63, wh = wi >> 3, ww = wi & 7;
    int rr = n / 7, cc = n - rr * 7;
    int hs = wh * 7 + rr + 3; if (hs >= 56) hs -= 56;
    int ws = ww * 7 + cc + 3; if (ws >= 56) ws -= 56;
    srcrow[reg] = bb * 3136 + hs * 56 + ws;
  }
#pragma unroll
  for (int nt = 0; nt < 12; ++nt)
#pragma unroll
    for (int reg = 0; reg < 4; ++reg)
      vals[nt][reg] = x[(size_t)srcrow[reg] * 192 + nt * 16 + c];
#pragma unroll
  for (int reg = 0; reg < 4; ++reg) {
    float s = 0.f;
#pragma unroll
    for (int nt = 0; nt < 12; ++nt) s += vals[nt][reg];
    s += __shfl_xor(s, 1, 64); s += __shfl_xor(s, 2, 64);
    s += __shfl_xor(s, 4, 64); s += __shfl_xor(s, 8, 64);
    float m = s * (1.f / 192.f), q = 0.f;
#pragma unroll
    for (int nt = 0; nt < 12; ++nt) { float d = vals[nt][reg] - m; q += d * d; }
    q += __shfl_xor(q, 1, 64); q += __shfl_xor(q, 2, 64);
    q += __shfl_xor(q, 4, 64); q += __shfl_xor(q, 8, 64);
    float rs = rsqrtf(q * (1.f / 192.f) + 1e-5f);
#pragma unroll
    for (int nt = 0; nt < 12; ++nt) vals[nt][reg] = (vals[nt][reg] - m) * rs;
  }
#pragma unroll
  for (int nt = 0; nt < 12; ++nt) {
    float wv = n1w[nt * 16 + c], bv = n1b[nt * 16 + c];
#pragma unroll
    for (int reg = 0; reg < 4; ++reg) {
      int r = wr + 4 * g + reg;
      int ch = nt * 2 + (c >> 3);
      int ph = (ch & 24) | ((ch ^ (r & 7)) & 7);
      sA[r * 192 + ph * 8 + (c & 7)] = f2b(vals[nt][reg] * wv + bv);
    }
  }
  __syncthreads();
  bf16x8 afr[6];
  {
    int ar = wr + c;
#pragma unroll
    for (int ks = 0; ks < 6; ++ks) {
      int ch = ks * 4 + g;
      int ph = (ch & 24) | ((ch ^ (ar & 7)) & 7);
      afr[ks] = *(const bf16x8*)(sA + ar * 192 + ph * 8);
    }
  }
  int win0 = tok0 / 49;
  for (int j = 0; j < 9; ++j) {
    u16* nb = (j & 1) ? sB0 : sB1;
    if (j < 8) {
      stage_64x192(qkvw + (size_t)(j + 1) * 64 * 192, 192, nb, wave, lane);
      asm volatile("s_waitcnt vmcnt(6)" ::: "memory");
    } else {
      asm volatile("s_waitcnt vmcnt(0)" ::: "memory");
    }
    __syncthreads();
    const u16* sb = (j & 1) ? sB1 : sB0;
    f32x4 S[4] = {{0,0,0,0},{0,0,0,0},{0,0,0,0},{0,0,0,0}};
#pragma unroll
    for (int ks = 0; ks < 6; ++ks)
#pragma unroll
      for (int nt = 0; nt < 4; ++nt) {
        int br = nt * 16 + c;
        int ch = ks * 4 + g;
        int ph = (ch & 24) | ((ch ^ (br & 7)) & 7);
        bf16x8 bf = *(const bf16x8*)(sb + br * 192 + ph * 8);
        S[nt] = MFMA16(afr[ks], bf, S[nt]);
      }
    int which = j / 3;  // 0=q 1=k 2=v (uniform per chunk)
    u16* dst = which == 0 ? qb : (which == 1 ? kb : vb);
#pragma unroll
    for (int nt = 0; nt < 4; ++nt) {
      int jc = j * 64 + nt * 16 + c;
      int jj = jc - which * 192;
      int hh = jj >> 5, d = jj & 31;
      float bv = qkvb_[jc];
#pragma unroll
      for (int reg = 0; reg < 4; ++reg) {
        int rg = tok0 + m0 + wr + 4 * g + reg;
        int win = rg / 49, n = rg - win * 49;
        dst[((size_t)((win - win0) * 6 + hh) * 49 + n) * 32 + d] =
            f2b(S[nt][reg] + bv);
      }
    }
    __syncthreads();
  }
}

// ---------------- attention: one (window, head) per block ----------------
__global__ __launch_bounds__(256) void attn_kernel(
    const u16* __restrict__ qb, const u16* __restrict__ kb,
    const u16* __restrict__ vb, const float* __restrict__ rpb,
    const float* __restrict__ amask, u16* __restrict__ aout, int win0) {
  __shared__ __align__(16) u16 qs[64 * 32], ks[64 * 32], vst[32 * 64];
  __shared__ __align__(16) float S[64 * 68];
  __shared__ __align__(16) u16 P[64 * 64];
  int tid = threadIdx.x;
  int blk = blockIdx.x;
  int winl = blk / 6, head = blk - winl * 6;
  int wi = (win0 + winl) & 63;
  const size_t base = (size_t)(winl * 6 + head) * 49 * 32;
  {
    int row = tid >> 2, kcl = tid & 3;
    int phys = kcl ^ (row & 3);
    uint4 qv = make_uint4(0, 0, 0, 0), kv = qv, vv = qv;
    if (row < 49) {
      size_t o = base + (size_t)row * 32 + kcl * 8;
      qv = *(const uint4*)(qb + o);
      kv = *(const uint4*)(kb + o);
      vv = *(const uint4*)(vb + o);
    }
    *(uint4*)(qs + row * 32 + phys * 8) = qv;
    *(uint4*)(ks + row * 32 + phys * 8) = kv;
    alignas(16) u16 vu[8];
    *(uint4*)vu = vv;
    int c8 = kcl * 8;
    int kc = row >> 3;
#pragma unroll
    for (int j = 0; j < 8; ++j) {
      int d = c8 + j;
      vst[d * 64 + ((kc ^ (d & 7)) * 8) + (row & 7)] = vu[j];
    }
  }
  __syncthreads();
  int wave = tid >> 6, lane = tid & 63;
  int col = lane & 15, g = lane >> 4;
  {
    int ar = wave * 16 + col;
    bf16x8 af = *(const bf16x8*)(qs + ar * 32 + ((g ^ (ar & 3)) * 8));
    f32x4 zero = {0.f, 0.f, 0.f, 0.f};
#pragma unroll
    for (int nt = 0; nt < 4; ++nt) {
      int br = nt * 16 + col;
      bf16x8 bfr = *(const bf16x8*)(ks + br * 32 + ((g ^ (br & 3)) * 8));
      f32x4 sacc = MFMA16(af, bfr, zero);
#pragma unroll
      for (int reg = 0; reg < 4; ++reg)
        S[(wave * 16 + 4 * g + reg) * 68 + nt * 16 + col] = sacc[reg];
    }
  }
  __syncthreads();
  {
    int r = tid >> 2, p = tid & 3;
    int rb = (r < 49) ? r : 0;
    int i1 = rb / 7, j1 = rb - i1 * 7;
    const float scale = 0.17677669529663687f;
    const float* Srow = S + r * 68;
    float vals[16];
    float mx = -1e30f;
#pragma unroll
    for (int t = 0; t < 16; ++t) {
      int cc = p * 16 + t;
      float v = -1e30f;
      if (cc < 49) {
        int i2 = cc / 7, j2 = cc - i2 * 7;
        int ridx = (i1 - i2 + 6) * 13 + (j1 - j2 + 6);
        v = Srow[cc] * scale + rpb[ridx * 6 + head] +
            amask[(size_t)wi * 2401 + rb * 49 + cc];
      }
      vals[t] = v;
      mx = fmaxf(mx, v);
    }
    mx = fmaxf(mx, __shfl_xor(mx, 1, 64));
    mx = fmaxf(mx, __shfl_xor(mx, 2, 64));
    float se = 0.f;
#pragma unroll
    for (int t = 0; t < 16; ++t) {
      float e = __expf(vals[t] - mx);
      vals[t] = e;
      se += e;
    }
    se += __shfl_xor(se, 1, 64);
    se += __shfl_xor(se, 2, 64);
    float inv = 1.0f / se;
#pragma unroll
    for (int t = 0; t < 16; ++t) {
      int cc = p * 16 + t;
      P[r * 64 + (((cc >> 3) ^ (r & 7)) * 8) + (cc & 7)] = f2b(vals[t] * inv);
    }
  }
  __syncthreads();
  {
    f32x4 oacc[2] = {{0,0,0,0},{0,0,0,0}};
    int ar = wave * 16 + col;
#pragma unroll
    for (int kt = 0; kt < 2; ++kt) {
      bf16x8 pf = *(const bf16x8*)(P + ar * 64 + (((kt * 4 + g) ^ (ar & 7)) * 8));
#pragma unroll
      for (int nt = 0; nt < 2; ++nt) {
        int d = nt * 16 + col;
        bf16x8 vf = *(const bf16x8*)(vst + d * 64 + (((kt * 4 + g) ^ (d & 7)) * 8));
        oacc[nt] = MFMA16(pf, vf, oacc[nt]);
      }
    }
#pragma unroll
    for (int nt = 0; nt < 2; ++nt)
#pragma unroll
      for (int reg = 0; reg < 4; ++reg) {
        int rloc = wave * 16 + 4 * g + reg;
        if (rloc < 49)
          aout[((size_t)winl * 49 + rloc) * 192 + head * 32 + nt * 16 + col] =
              f2b(oacc[nt][reg]);
      }
  }
}

// ---------------- fused proj GEMM + window reverse + unshift + residual ----------------
__global__ __launch_bounds__(256, 2) void proj_fused(
    const u16* __restrict__ aout, const u16* __restrict__ projw,
    const float* __restrict__ pb, const float* __restrict__ x,
    float* __restrict__ out, int tok0) {
  __shared__ __align__(16) u16 lds[36864];
  u16* sA = lds;
  u16* sB0 = lds + 12288;
  u16* sB1 = lds + 24576;
  int tid = threadIdx.x, wave = tid >> 6, lane = tid & 63;
  int g = lane >> 4, c = lane & 15, wr = wave * 16;
  int m0 = blockIdx.x * 64;
  stage_64x192(aout + (size_t)m0 * 192, 192, sA, wave, lane);
  stage_64x192(projw, 192, sB0, wave, lane);
  asm volatile("s_waitcnt vmcnt(0)" ::: "memory");
  __syncthreads();
  bf16x8 afr[6];
  {
    int ar = wr + c;
#pragma unroll
    for (int ks = 0; ks < 6; ++ks) {
      int ch = ks * 4 + g;
      int ph = (ch & 24) | ((ch ^ (ar & 7)) & 7);
      afr[ks] = *(const bf16x8*)(sA + ar * 192 + ph * 8);
    }
  }
  // row -> output token mapping (window reverse + unshift)
  size_t trow[4];
#pragma unroll
  for (int reg = 0; reg < 4; ++reg) {
    int rg = tok0 + m0 + wr + 4 * g + reg;
    int win = rg / 49, n = rg - win * 49;
    int b_ = win >> 6, wi = win & 63;
    int wh = wi >> 3, ww = wi & 7;
    int rr = n / 7, cc = n - rr * 7;
    int hd_ = wh * 7 + rr + 3; if (hd_ >= 56) hd_ -= 56;
    int wd = ww * 7 + cc + 3; if (wd >= 56) wd -= 56;
    trow[reg] = (size_t)b_ * 3136 + hd_ * 56 + wd;
  }
  for (int j = 0; j < 3; ++j) {
    if (j < 2) {
      u16* nb = (j & 1) ? sB0 : sB1;
      stage_64x192(projw + (size_t)(j + 1) * 64 * 192, 192, nb, wave, lane);
      asm volatile("s_waitcnt vmcnt(6)" ::: "memory");
    } else {
      asm volatile("s_waitcnt vmcnt(0)" ::: "memory");
    }
    __syncthreads();
    const u16* sb = (j & 1) ? sB1 : sB0;
    f32x4 S[4] = {{0,0,0,0},{0,0,0,0},{0,0,0,0},{0,0,0,0}};
#pragma unroll
    for (int ks = 0; ks < 6; ++ks)
#pragma unroll
      for (int nt = 0; nt < 4; ++nt) {
        int br = nt * 16 + c;
        int ch = ks * 4 + g;
        int ph = (ch & 24) | ((ch ^ (br & 7)) & 7);
        bf16x8 bf = *(const bf16x8*)(sb + br * 192 + ph * 8);
        S[nt] = MFMA16(afr[ks], bf, S[nt]);
      }
#pragma unroll
    for (int nt = 0; nt < 4; ++nt) {
      int jc = j * 64 + nt * 16 + c;
      float bv = pb[jc];
#pragma unroll
      for (int reg = 0; reg < 4; ++reg) {
        size_t o = trow[reg] * 192 + jc;
        out[o] = x[o] + S[nt][reg] + bv;
      }
    }
    __syncthreads();
  }
}

// ---------------- fused LN2 + fc1 + GELU + fc2 + residual ----------------
__global__ __launch_bounds__(256, 2) void mlp_fused(
    const float* __restrict__ n2w, const float* __restrict__ n2b,
    const u16* __restrict__ w1, const float* __restrict__ b1,
    const u16* __restrict__ w2, const float* __restrict__ b2,
    float* __restrict__ out) {
  __shared__ __align__(16) u16 lds[36864];
  u16* sA = lds;       // 64x192; first 4096 u16 reused as sP (64x64)
  u16* sP = lds;
  u16* sB1 = lds + 12288;
  u16* sB2 = lds + 24576;
  int tid = threadIdx.x, wave = tid >> 6, lane = tid & 63;
  int g = lane >> 4, c = lane & 15, wr = wave * 16;
  int m0 = blockIdx.x * 64;
  // prefetch chunk-0 weights while doing LN
  stage_64x192(w1, 192, sB1, wave, lane);
  stage_192x64(w2, 768, sB2, wave, lane);
  // LN2 in C-layout registers; residual kept in regs
  float resid[12][4];
  int rowg[4];
#pragma unroll
  for (int reg = 0; reg < 4; ++reg) rowg[reg] = m0 + wr + 4 * g + reg;
#pragma unroll
  for (int nt = 0; nt < 12; ++nt)
#pragma unroll
    for (int reg = 0; reg < 4; ++reg)
      resid[nt][reg] = out[(size_t)rowg[reg] * 192 + nt * 16 + c];
  float mean[4], rstd[4];
#pragma unroll
  for (int reg = 0; reg < 4; ++reg) {
    float s = 0.f;
#pragma unroll
    for (int nt = 0; nt < 12; ++nt) s += resid[nt][reg];
    s += __shfl_xor(s, 1, 64); s += __shfl_xor(s, 2, 64);
    s += __shfl_xor(s, 4, 64); s += __shfl_xor(s, 8, 64);
    float m = s * (1.f / 192.f), q = 0.f;
#pragma unroll
    for (int nt = 0; nt < 12; ++nt) { float d = resid[nt][reg] - m; q += d * d; }
    q += __shfl_xor(q, 1, 64); q += __shfl_xor(q, 2, 64);
    q += __shfl_xor(q, 4, 64); q += __shfl_xor(q, 8, 64);
    mean[reg] = m;
    rstd[reg] = rsqrtf(q * (1.f / 192.f) + 1e-5f);
  }
#pragma unroll
  for (int nt = 0; nt < 12; ++nt) {
    float wv = n2w[nt * 16 + c], bv = n2b[nt * 16 + c];
#pragma unroll
    for (int reg = 0; reg < 4; ++reg) {
      int r = wr + 4 * g + reg;
      float v = (resid[nt][reg] - mean[reg]) * rstd[reg] * wv + bv;
      int ch = nt * 2 + (c >> 3);
      int ph = (ch & 24) | ((ch ^ (r & 7)) & 7);
      sA[r * 192 + ph * 8 + (c & 7)] = f2b(v);
    }
  }
  __syncthreads();
  bf16x8 afr[6];
  {
    int ar = wr + c;
#pragma unroll
    for (int ks = 0; ks < 6; ++ks) {
      int ch = ks * 4 + g;
      int ph = (ch & 24) | ((ch ^ (ar & 7)) & 7);
      afr[ks] = *(const bf16x8*)(sA + ar * 192 + ph * 8);
    }
  }
  asm volatile("s_waitcnt vmcnt(0)" ::: "memory");
  __syncthreads();  // afr reads done in all waves (sP writes now safe); B0 staged
  f32x4 oacc[12];
#pragma unroll
  for (int i = 0; i < 12; ++i) oacc[i] = (f32x4){0.f, 0.f, 0.f, 0.f};
  for (int j = 0; j < 12; ++j) {
    // S = A @ fc1_chunk^T
    f32x4 S[4] = {{0,0,0,0},{0,0,0,0},{0,0,0,0},{0,0,0,0}};
#pragma unroll
    for (int ks = 0; ks < 6; ++ks)
#pragma unroll
      for (int nt = 0; nt < 4; ++nt) {
        int br = nt * 16 + c;
        int ch = ks * 4 + g;
        int ph = (ch & 24) | ((ch ^ (br & 7)) & 7);
        bf16x8 bf = *(const bf16x8*)(sB1 + br * 192 + ph * 8);
        S[nt] = MFMA16(afr[ks], bf, S[nt]);
      }
    // GELU -> P tile (overlays sA; PV(j-1) readers done at end-of-iter barrier)
#pragma unroll
    for (int nt = 0; nt < 4; ++nt) {
      float bv = b1[j * 64 + nt * 16 + c];
#pragma unroll
      for (int reg = 0; reg < 4; ++reg) {
        int r = wr + 4 * g + reg;
        float v = S[nt][reg] + bv;
        float gl = 0.5f * v * (1.0f + erff(v * 0.70710678118654752f));
        int col = nt * 16 + c;
        int ph = (col >> 3) ^ (r & 7);
        sP[r * 64 + ph * 8 + (col & 7)] = f2b(gl);
      }
    }
    __syncthreads();  // P visible; all S-reads of sB1 done
    // oacc += P @ fc2_chunk
#pragma unroll
    for (int ks = 0; ks < 2; ++ks) {
      int pr = wr + c;
      int ch = ks * 4 + g;
      bf16x8 pf = *(const bf16x8*)(sP + pr * 64 + (ch ^ (pr & 7)) * 8);
#pragma unroll
      for (int nt = 0; nt < 12; ++nt) {
        int c2 = nt * 16 + c;
        bf16x8 bf = *(const bf16x8*)(sB2 + c2 * 64 + (ch ^ (c2 & 7)) * 8);
        oacc[nt] = MFMA16(pf, bf, oacc[nt]);
      }
    }
    __syncthreads();  // PV done in all waves -> safe to restage
    if (j < 11) {
      stage_64x192(w1 + (size_t)(j + 1) * 64 * 192, 192, sB1, wave, lane);
      stage_192x64(w2 + (size_t)(j + 1) * 64, 768, sB2, wave, lane);
      asm volatile("s_waitcnt vmcnt(0)" ::: "memory");
    }
    __syncthreads();  // staged data visible
  }
  // epilogue: residual + bias
#pragma unroll
  for (int nt = 0; nt < 12; ++nt) {
    float bv = b2[nt * 16 + c];
#pragma unroll
    for (int reg = 0; reg < 4; ++reg) {
      size_t o = (size_t)rowg[reg] * 192 + nt * 16 + c;
      out[o] = resid[nt][reg] + oacc[nt][reg] + bv;
    }
  }
}

extern "C" void kernel_launch(void* const* d_in, const int* in_sizes, int n_in,
                              void* d_out, int out_size, void* d_ws, size_t ws_size,
                              hipStream_t stream) {
  (void)in_sizes; (void)n_in; (void)out_size;
  const float* x     = (const float*)d_in[0];
  const float* amask = (const float*)d_in[1];
  const float* n1w   = (const float*)d_in[2];
  const float* n1b   = (const float*)d_in[3];
  const float* qkvw  = (const float*)d_in[4];
  const float* qkvb  = (const float*)d_in[5];
  const float* rpb   = (const float*)d_in[6];
  const float* projw = (const float*)d_in[7];
  const float* projb = (const float*)d_in[8];
  const float* n2w   = (const float*)d_in[9];
  const float* n2b   = (const float*)d_in[10];
  const float* fc1w  = (const float*)d_in[11];
  const float* fc1b  = (const float*)d_in[12];
  const float* fc2w  = (const float*)d_in[13];
  const float* fc2b  = (const float*)d_in[14];
  float* out = (float*)d_out;
  char* ws = (char*)d_ws;

  u16* qkvw_bf = (u16*)(ws);
  u16* projw_bf = (u16*)(ws + 221184);
  u16* fc1w_bf = (u16*)(ws + 221184 + 73728);
  u16* fc2w_bf = (u16*)(ws + 221184 + 73728 + 294912);
  char* arena = ws + (1 << 20);
  size_t arena_sz = ws_size > (1 << 20) ? ws_size - (1 << 20) : 0;

  cvt_kernel<<<(110592 + 255) / 256, 256, 0, stream>>>(qkvw, qkvw_bf, 110592);
  cvt_kernel<<<(36864 + 255) / 256, 256, 0, stream>>>(projw, projw_bf, 36864);
  cvt_kernel<<<(147456 + 255) / 256, 256, 0, stream>>>(fc1w, fc1w_bf, 147456);
  cvt_kernel<<<(147456 + 255) / 256, 256, 0, stream>>>(fc2w, fc2w_bf, 147456);

  // ---- attention path, chunked over window groups (ws-size adaptive) ----
  int NCA = 1;
  while (NCA < 16 && 4ull * (size_t)(2048 / NCA) * 49 * 192 * 2 > arena_sz)
    NCA <<= 1;
  int Wc = 2048 / NCA;
  size_t Sx = (size_t)Wc * 49 * 192;  // u16 elements per buffer
  for (int cch = 0; cch < NCA; ++cch) {
    int win0 = cch * Wc;
    int tok0 = win0 * 49;
    u16* aout_c = (u16*)arena;
    u16* qb = (u16*)arena + Sx;
    u16* kb = qb + Sx;
    u16* vb = kb + Sx;
    int rows = Wc * 49;
    qkv_fused<<<rows / 64, 256, 0, stream>>>(x, n1w, n1b, qkvw_bf, qkvb,
                                             qb, kb, vb, tok0);
    attn_kernel<<<Wc * 6, 256, 0, stream>>>(qb, kb, vb, rpb, amask, aout_c,
                                            win0);
    proj_fused<<<rows / 64, 256, 0, stream>>>(aout_c, projw_bf, projb, x, out,
                                              tok0);
  }

  // ---- fused MLP (no intermediates -> no chunking) ----
  mlp_fused<<<1568, 256, 0, stream>>>(n2w, n2b, fc1w_bf, fc1b, fc2w_bf, fc2b,
                                      out);
}